// Round 1
// baseline (753.200 us; speedup 1.0000x reference)
//
#include <hip/hip_runtime.h>
#include <hip/hip_bf16.h>
#include <math.h>

// TransBlock on MI355X (gfx950). bf16 MFMA everywhere (threshold = 2% of absmax).
// Pipeline: stats1 -> ln_qkv(bf16) -> QKV gemm(z=3) -> vtrans -> fused attn
//   (QK^T + softmax-one + weights-write + PV + residual) -> stats2 ->
//   ln+transpose -> conv1 gemm(+GELU, h1^T) -> conv2 gemm(+bias+residual, fp32 out)
// Scratch: ~72 MB of d_ws; ln_qkv outputs live in d_out's attn-weights region
// (dead before attention overwrites it).

typedef __bf16 bf16;
typedef __bf16 bf16x4 __attribute__((ext_vector_type(4)));
typedef __bf16 bf16x8 __attribute__((ext_vector_type(8)));
typedef float floatx4 __attribute__((ext_vector_type(4)));

#define MFMA16(a, b, c) __builtin_amdgcn_mfma_f32_16x16x32_bf16(a, b, c, 0, 0, 0)

__device__ __forceinline__ void gload16(const void* g, void* l) {
    __builtin_amdgcn_global_load_lds((__attribute__((address_space(1))) void*)g,
                                     (__attribute__((address_space(3))) void*)l,
                                     16, 0, 0);
}

// ---------------- cast fp32 -> bf16 for the 5 weight matrices ----------------
__global__ __launch_bounds__(256)
void cast_all(const float* __restrict__ s0, bf16* __restrict__ d0_,
              const float* __restrict__ s1, bf16* __restrict__ d1_,
              const float* __restrict__ s2, bf16* __restrict__ d2_,
              const float* __restrict__ s3, bf16* __restrict__ d3_,
              const float* __restrict__ s4, bf16* __restrict__ d4_)
{
    int blk = blockIdx.x;
    const float* s; bf16* d; int base;
    if (blk < 1024)      { s = s0; d = d0_; base = blk; }
    else if (blk < 2048) { s = s1; d = d1_; base = blk - 1024; }
    else if (blk < 3072) { s = s2; d = d2_; base = blk - 2048; }
    else if (blk < 7168) { s = s3; d = d3_; base = blk - 3072; }
    else                 { s = s4; d = d4_; base = blk - 7168; }
    long i = ((long)base << 10) + (threadIdx.x << 2);
    float4 v = *(const float4*)(s + i);
    bf16x4 o;
    o[0] = (bf16)v.x; o[1] = (bf16)v.y; o[2] = (bf16)v.z; o[3] = (bf16)v.w;
    *(bf16x4*)(d + i) = o;
}

// ---------------- column LayerNorm stats: mean/rstd over C per (b,d) ----------
__global__ __launch_bounds__(256)
void stats_kernel(const float* __restrict__ xin, float* __restrict__ u,
                  float* __restrict__ rstd)
{
    __shared__ float S1[4][64];
    __shared__ float S2[4][64];
    const int b = blockIdx.y;
    const int d0 = blockIdx.x << 6;
    const int tid = threadIdx.x;
    const int dl = tid & 63, cg = tid >> 6;
    const float* xp = xin + ((long)b << 20) + d0 + dl;
    float s = 0.f, sq = 0.f;
    const int cbase = cg << 8;
    for (int c = 0; c < 256; ++c) {
        float v = xp[(long)(cbase + c) << 10];
        s += v; sq += v * v;
    }
    S1[cg][dl] = s; S2[cg][dl] = sq;
    __syncthreads();
    if (tid < 64) {
        float ts = S1[0][tid] + S1[1][tid] + S1[2][tid] + S1[3][tid];
        float tq = S2[0][tid] + S2[1][tid] + S2[2][tid] + S2[3][tid];
        float mu = ts * (1.f / 1024.f);
        float var = tq * (1.f / 1024.f) - mu * mu;
        u[(b << 10) + d0 + tid] = mu;
        rstd[(b << 10) + d0 + tid] = rsqrtf(var + 1e-6f);
    }
}

// ------------- normalize x1 three ways (q/k/v scale+shift), cast bf16 ---------
__global__ __launch_bounds__(256)
void ln_qkv_kernel(const float* __restrict__ x1, const float* __restrict__ u,
                   const float* __restrict__ rs,
                   const float* __restrict__ wq, const float* __restrict__ bq,
                   const float* __restrict__ wk, const float* __restrict__ bk,
                   const float* __restrict__ wv, const float* __restrict__ bv,
                   bf16* __restrict__ lnq, bf16* __restrict__ lnk,
                   bf16* __restrict__ lnv)
{
    const int bc = blockIdx.x;             // b*1024 + c  (one row per block)
    const int c = bc & 1023, b = bc >> 10;
    const int d = threadIdx.x << 2;
    const long i = ((long)bc << 10) + d;
    const float4 xv = *(const float4*)(x1 + i);
    const float4 uv = *(const float4*)(u + (b << 10) + d);
    const float4 rv = *(const float4*)(rs + (b << 10) + d);
    float xn0 = (xv.x - uv.x) * rv.x;
    float xn1 = (xv.y - uv.y) * rv.y;
    float xn2 = (xv.z - uv.z) * rv.z;
    float xn3 = (xv.w - uv.w) * rv.w;
    float sw, sb; bf16x4 o;
    sw = wq[c]; sb = bq[c];
    o[0]=(bf16)(sw*xn0+sb); o[1]=(bf16)(sw*xn1+sb); o[2]=(bf16)(sw*xn2+sb); o[3]=(bf16)(sw*xn3+sb);
    *(bf16x4*)(lnq + i) = o;
    sw = wk[c]; sb = bk[c];
    o[0]=(bf16)(sw*xn0+sb); o[1]=(bf16)(sw*xn1+sb); o[2]=(bf16)(sw*xn2+sb); o[3]=(bf16)(sw*xn3+sb);
    *(bf16x4*)(lnk + i) = o;
    sw = wv[c]; sb = bv[c];
    o[0]=(bf16)(sw*xn0+sb); o[1]=(bf16)(sw*xn1+sb); o[2]=(bf16)(sw*xn2+sb); o[3]=(bf16)(sw*xn3+sb);
    *(bf16x4*)(lnv + i) = o;
}

// --------- m97-style BT GEMM: out[m,n] = sum_k A[m,k]*B[n,k], 128x128 tile ----
// mode 0: out bf16 = acc + bias[n]            (QKV; bias selected by z)
// mode 1: out bf16 = gelu(acc + bias[n])      (conv1 -> h1^T)
// mode 2: out fp32 = acc + bias[m] + resid    (conv2 -> final out0)
__global__ __launch_bounds__(256)
void gemm_bt(const bf16* __restrict__ Ab, const bf16* __restrict__ Bb,
             void* __restrict__ Outb,
             const float* __restrict__ bias0, const float* __restrict__ bias1,
             const float* __restrict__ bias2, const float* __restrict__ residb,
             long sAz, long sBz, long sOz, long sRz,
             int M, int N, int K, int mode)
{
    __shared__ __align__(16) bf16 As[128 * 32];
    __shared__ __align__(16) bf16 Bs[128 * 32];
    const int z = blockIdx.z;
    const bf16* A = Ab + (long)z * sAz;
    const bf16* B = Bb + (long)z * sBz;
    const float* bias = (z == 0) ? bias0 : (z == 1 ? bias1 : bias2);
    const int m0 = blockIdx.y << 7, n0 = blockIdx.x << 7;
    const int tid = threadIdx.x;
    const int wave = tid >> 6, lane = tid & 63;
    const int wm = (wave & 1) << 6, wn = (wave >> 1) << 6;
    const int lm = lane & 15, lk = (lane >> 4) << 3;
    floatx4 acc[4][4] = {};
    for (int kt = 0; kt < K; kt += 32) {
        const bf16* Ag = A + (long)m0 * K + kt;
        const bf16* Bg = B + (long)n0 * K + kt;
#pragma unroll
        for (int i = 0; i < 2; ++i) {
            int c = tid + (i << 8);
            int row = c >> 2, kc = (c & 3) << 3;
            gload16(Ag + (long)row * K + kc, As + c * 8);
            gload16(Bg + (long)row * K + kc, Bs + c * 8);
        }
        __syncthreads();
        bf16x8 af[4], bfv[4];
#pragma unroll
        for (int mi = 0; mi < 4; ++mi)
            af[mi] = *(const bf16x8*)(As + (wm + mi * 16 + lm) * 32 + lk);
#pragma unroll
        for (int ni = 0; ni < 4; ++ni)
            bfv[ni] = *(const bf16x8*)(Bs + (wn + ni * 16 + lm) * 32 + lk);
#pragma unroll
        for (int mi = 0; mi < 4; ++mi)
#pragma unroll
            for (int ni = 0; ni < 4; ++ni)
                acc[mi][ni] = MFMA16(af[mi], bfv[ni], acc[mi][ni]);
        __syncthreads();
    }
    const int quad = lane >> 4;
    if (mode == 2) {
        float* Out = (float*)Outb + (long)z * sOz;
        const float* R = residb + (long)z * sRz;
#pragma unroll
        for (int mi = 0; mi < 4; ++mi)
#pragma unroll
            for (int ni = 0; ni < 4; ++ni)
#pragma unroll
                for (int r = 0; r < 4; ++r) {
                    int row = m0 + wm + mi * 16 + quad * 4 + r;
                    int col = n0 + wn + ni * 16 + lm;
                    long idx = (long)row * N + col;
                    Out[idx] = acc[mi][ni][r] + bias[row] + R[idx];
                }
    } else {
        bf16* Out = (bf16*)Outb + (long)z * sOz;
#pragma unroll
        for (int mi = 0; mi < 4; ++mi)
#pragma unroll
            for (int ni = 0; ni < 4; ++ni)
#pragma unroll
                for (int r = 0; r < 4; ++r) {
                    int row = m0 + wm + mi * 16 + quad * 4 + r;
                    int col = n0 + wn + ni * 16 + lm;
                    float v = acc[mi][ni][r] + bias[col];
                    if (mode == 1)
                        v = 0.5f * v * (1.0f + erff(v * 0.70710678118654752f));
                    Out[(long)row * N + col] = (bf16)v;
                }
    }
}

// ---------------- V slab transpose: VT[p][e][k] = V[p][k][e] ------------------
__global__ __launch_bounds__(256)
void vtrans_kernel(const bf16* __restrict__ v, bf16* __restrict__ vt)
{
    __shared__ bf16 T[64][66];
    const int p = blockIdx.y;
    const int k0 = blockIdx.x << 6;
    const bf16* V = v + ((long)p << 16);
    bf16* Vt = vt + ((long)p << 16);
    const int tid = threadIdx.x;
    const int e = tid & 63, g = tid >> 6;
#pragma unroll
    for (int j = 0; j < 16; ++j) {
        int kk = (g << 4) + j;
        T[e][kk] = V[((long)(k0 + kk) << 6) + e];
    }
    __syncthreads();
#pragma unroll
    for (int j = 0; j < 16; ++j) {
        int er = (g << 4) + j;
        Vt[((long)er << 10) + k0 + e] = T[er][e];
    }
}

// ------- fused attention: S=QK^T/8, softmax-one, write weights, PV, +x1 -------
// block = (16 q-rows) x (full 1024 k), 4 waves k-split 256 each.
__global__ __launch_bounds__(256)
void attn_kernel(const bf16* __restrict__ q, const bf16* __restrict__ k,
                 const bf16* __restrict__ vt, const float* __restrict__ x1,
                 float* __restrict__ attw, float* __restrict__ x)
{
    __shared__ __align__(16) bf16 Wl[16][1032];   // weights (bf16) for PV A-operand
    __shared__ float red[16][4];
    const int s = blockIdx.x;            // q-stripe 0..63
    const int p = blockIdx.y;            // (b,h) 0..63
    const int b = p >> 4, h = p & 15;
    const bf16* Qp = q + ((long)b << 20) + ((long)h << 16);
    const bf16* Kp = k + ((long)b << 20) + ((long)h << 16);
    const bf16* Vt = vt + ((long)p << 16);
    const int tid = threadIdx.x, w = tid >> 6, lane = tid & 63;
    const int lm = lane & 15, quad = lane >> 4;
    const int r0 = s << 4, kc0 = w << 8;

    floatx4 acc[16];
#pragma unroll
    for (int t = 0; t < 16; ++t) acc[t] = (floatx4){0.f, 0.f, 0.f, 0.f};

#pragma unroll
    for (int e0 = 0; e0 < 64; e0 += 32) {
        bf16x8 aq = *(const bf16x8*)(Qp + ((long)(r0 + lm) << 6) + e0 + quad * 8);
#pragma unroll
        for (int t = 0; t < 16; ++t) {
            bf16x8 bk = *(const bf16x8*)(Kp + ((long)(kc0 + t * 16 + lm) << 6) + e0 + quad * 8);
            acc[t] = MFMA16(aq, bk, acc[t]);
        }
    }
#pragma unroll
    for (int t = 0; t < 16; ++t)
#pragma unroll
        for (int r = 0; r < 4; ++r) acc[t][r] *= 0.125f;   // 1/sqrt(64)

    // row for (quad, r) is quad*4+r; its 256 wave-local cols live on the 16 lanes of the quad
    float mloc[4];
#pragma unroll
    for (int r = 0; r < 4; ++r) {
        float mm = acc[0][r];
#pragma unroll
        for (int t = 1; t < 16; ++t) mm = fmaxf(mm, acc[t][r]);
        mloc[r] = mm;
    }
#pragma unroll
    for (int off = 1; off < 16; off <<= 1)
#pragma unroll
        for (int r = 0; r < 4; ++r) mloc[r] = fmaxf(mloc[r], __shfl_xor(mloc[r], off, 64));
    if (lm == 0)
#pragma unroll
        for (int r = 0; r < 4; ++r) red[quad * 4 + r][w] = mloc[r];
    __syncthreads();
    float mfin[4];
#pragma unroll
    for (int r = 0; r < 4; ++r) {
        int row = quad * 4 + r;
        mfin[r] = fmaxf(fmaxf(red[row][0], red[row][1]), fmaxf(red[row][2], red[row][3]));
    }
    float sloc[4] = {0.f, 0.f, 0.f, 0.f};
#pragma unroll
    for (int t = 0; t < 16; ++t)
#pragma unroll
        for (int r = 0; r < 4; ++r) {
            float e = __expf(acc[t][r] - mfin[r]);
            acc[t][r] = e;
            sloc[r] += e;
        }
#pragma unroll
    for (int off = 1; off < 16; off <<= 1)
#pragma unroll
        for (int r = 0; r < 4; ++r) sloc[r] += __shfl_xor(sloc[r], off, 64);
    __syncthreads();   // all mfin reads done before red is overwritten
    if (lm == 0)
#pragma unroll
        for (int r = 0; r < 4; ++r) red[quad * 4 + r][w] = sloc[r];
    __syncthreads();
    float inv[4];
#pragma unroll
    for (int r = 0; r < 4; ++r) {
        int row = quad * 4 + r;
        inv[r] = 1.f / (1.f + red[row][0] + red[row][1] + red[row][2] + red[row][3]);
    }
    // write weights (fp32 out) + bf16 copy into LDS for PV
    float* attp = attw + ((long)p << 20) + ((long)r0 << 10) + kc0;
#pragma unroll
    for (int r = 0; r < 4; ++r) {
        int row = quad * 4 + r;
        float iv = inv[r];
#pragma unroll
        for (int t = 0; t < 16; ++t) {
            float wv = acc[t][r] * iv;
            attp[((long)row << 10) + t * 16 + lm] = wv;
            Wl[row][kc0 + t * 16 + lm] = (bf16)wv;
        }
    }
    __syncthreads();

    // PV: O(16x64) = W(16x1024) @ V(1024x64), wave w covers k in [kc0,kc0+256)
    floatx4 opv[4];
#pragma unroll
    for (int ni = 0; ni < 4; ++ni) opv[ni] = (floatx4){0.f, 0.f, 0.f, 0.f};
#pragma unroll
    for (int i = 0; i < 8; ++i) {
        const int kk = kc0 + i * 32;
        bf16x8 a0 = *(const bf16x8*)&Wl[lm][kk + quad * 8];
#pragma unroll
        for (int ni = 0; ni < 4; ++ni) {
            bf16x8 bv = *(const bf16x8*)(Vt + ((long)(ni * 16 + lm) << 10) + kk + quad * 8);
            opv[ni] = MFMA16(a0, bv, opv[ni]);
        }
    }
    __syncthreads();
    float* Ored = (float*)&Wl[0][0];   // [4][16][64], aliases Wl (dead now)
#pragma unroll
    for (int ni = 0; ni < 4; ++ni)
#pragma unroll
        for (int r = 0; r < 4; ++r)
            Ored[(w * 16 + quad * 4 + r) * 64 + ni * 16 + lm] = opv[ni][r];
    __syncthreads();
    const float* x1p = x1 + ((long)b << 20) + ((long)r0 << 10) + (h << 6);
    float* xp = x + ((long)b << 20) + ((long)r0 << 10) + (h << 6);
#pragma unroll
    for (int j = 0; j < 4; ++j) {
        int el = tid + (j << 8);
        int row = el >> 6, cc = el & 63;
        float o = Ored[row * 64 + cc] + Ored[(16 + row) * 64 + cc]
                + Ored[(32 + row) * 64 + cc] + Ored[(48 + row) * 64 + cc];
        xp[((long)row << 10) + cc] = x1p[((long)row << 10) + cc] + o;
    }
}

// --------- FFN LN + transpose: xlT[b][l][c] = ffw[c]*(x-u)*rstd + ffb[c] ------
__global__ __launch_bounds__(256)
void ln_ffn_t_kernel(const float* __restrict__ x, const float* __restrict__ u2,
                     const float* __restrict__ r2, const float* __restrict__ fw,
                     const float* __restrict__ fb, bf16* __restrict__ xlT)
{
    __shared__ bf16 T[64][66];
    const int b = blockIdx.z;
    const int l0 = blockIdx.x << 6, c0 = blockIdx.y << 6;
    const int tid = threadIdx.x;
    const int ll = tid & 63, g = tid >> 6;
    const float uu = u2[(b << 10) + l0 + ll];
    const float rr = r2[(b << 10) + l0 + ll];
#pragma unroll
    for (int j = 0; j < 16; ++j) {
        int cc = (g << 4) + j;
        float v = x[((long)b << 20) + ((long)(c0 + cc) << 10) + l0 + ll];
        T[ll][cc] = (bf16)(fw[c0 + cc] * (v - uu) * rr + fb[c0 + cc]);
    }
    __syncthreads();
#pragma unroll
    for (int j = 0; j < 16; ++j) {
        int lr = (g << 4) + j;
        xlT[((long)b << 20) + ((long)(l0 + lr) << 10) + c0 + ll] = T[lr][ll];
    }
}

extern "C" void kernel_launch(void* const* d_in, const int* in_sizes, int n_in,
                              void* d_out, int out_size, void* d_ws, size_t ws_size,
                              hipStream_t stream)
{
    const float* x1      = (const float*)d_in[0];
    const float* lnq_w   = (const float*)d_in[1];
    const float* lnq_b   = (const float*)d_in[2];
    const float* lnk_w   = (const float*)d_in[3];
    const float* lnk_b   = (const float*)d_in[4];
    const float* lnv_w   = (const float*)d_in[5];
    const float* lnv_b   = (const float*)d_in[6];
    const float* wq      = (const float*)d_in[7];
    const float* bq      = (const float*)d_in[8];
    const float* wk      = (const float*)d_in[9];
    const float* bk      = (const float*)d_in[10];
    const float* wv      = (const float*)d_in[11];
    const float* bv      = (const float*)d_in[12];
    const float* ffnln_w = (const float*)d_in[13];
    const float* ffnln_b = (const float*)d_in[14];
    const float* conv1_w = (const float*)d_in[15];
    const float* conv1_b = (const float*)d_in[16];
    const float* conv2_w = (const float*)d_in[17];
    const float* conv2_b = (const float*)d_in[18];
    (void)in_sizes; (void)n_in; (void)out_size; (void)ws_size;

    char* ws = (char*)d_ws;
    // ws layout (bytes); overlays are liveness-safe (see timeline in comments)
    const size_t OFF_VT   = 65536;                    //  8 MB  VT      [h1T overlay start]
    const size_t OFF_QKV  = OFF_VT  + 8388608;        // 24 MB  q,k,v bf16
    const size_t OFF_WQKV = OFF_QKV + 25165824;       //  8 MB region (6 used) wq/wk/wv bf16 [xlT overlay]
    const size_t OFF_X    = OFF_WQKV + 8388608;       // 16 MB  x = x1 + attn_out (fp32)
    const size_t OFF_W1   = OFF_X   + 16777216;       //  8 MB  conv1_w bf16
    const size_t OFF_W2   = OFF_W1  + 8388608;        //  8 MB  conv2_w bf16
    float* u1    = (float*)(ws + 0);
    float* rstd1 = (float*)(ws + 16384);
    float* u2    = (float*)(ws + 32768);
    float* r2    = (float*)(ws + 49152);
    bf16*  vt    = (bf16*)(ws + OFF_VT);
    bf16*  qkv   = (bf16*)(ws + OFF_QKV);
    bf16*  wqkvb = (bf16*)(ws + OFF_WQKV);
    float* x     = (float*)(ws + OFF_X);
    bf16*  w1b   = (bf16*)(ws + OFF_W1);
    bf16*  w2b   = (bf16*)(ws + OFF_W2);
    bf16*  h1T   = (bf16*)(ws + OFF_VT);              // 32 MB, overlays vt+qkv (dead post-attn)
    bf16*  xlT   = (bf16*)(ws + OFF_WQKV);            //  8 MB, overlays wqkvb (dead post-QKV gemm)

    float* out0 = (float*)d_out;
    float* attw = (float*)((char*)d_out + 16777216);  // 4*16*1024*1024 fp32
    bf16*  lnqkv = (bf16*)attw;                       // 24 MB scratch, dead before attn writes

    // 1. weight casts
    cast_all<<<11264, 256, 0, stream>>>(wq, wqkvb, wk, wqkvb + (1 << 20),
                                        wv, wqkvb + (2 << 20), conv1_w, w1b, conv2_w, w2b);
    // 2. LN stats of x1
    stats_kernel<<<dim3(16, 4), 256, 0, stream>>>(x1, u1, rstd1);
    // 3. normalized q/k/v inputs (bf16)
    ln_qkv_kernel<<<4096, 256, 0, stream>>>(x1, u1, rstd1, lnq_w, lnq_b, lnk_w, lnk_b,
                                            lnv_w, lnv_b, lnqkv, lnqkv + (1L << 22),
                                            lnqkv + (2L << 22));
    // 4. QKV projections (z=0/1/2), bf16 out + bias
    gemm_bt<<<dim3(8, 32, 3), 256, 0, stream>>>(lnqkv, wqkvb, qkv, bq, bk, bv, nullptr,
                                                1L << 22, 1L << 20, 1L << 22, 0,
                                                4096, 1024, 1024, 0);
    // 5. V^T slabs for PV B-operand
    vtrans_kernel<<<dim3(16, 64), 256, 0, stream>>>(qkv + (2L << 22), vt);
    // 6. fused attention (writes attn weights fp32 + x = x1 + o)
    attn_kernel<<<dim3(64, 64), 256, 0, stream>>>(qkv, qkv + (1L << 22), vt, x1, attw, x);
    // 7. FFN LN stats of x
    stats_kernel<<<dim3(16, 4), 256, 0, stream>>>(x, u2, r2);
    // 8. FFN LN + transpose -> xlT (bf16)
    ln_ffn_t_kernel<<<dim3(16, 16, 4), 256, 0, stream>>>(x, u2, r2, ffnln_w, ffnln_b, xlT);
    // 9. conv1: h1T[b] = gelu(xlT[b] @ conv1_w^T + b1)   (M=1024,N=4096,K=1024)
    gemm_bt<<<dim3(32, 8, 4), 256, 0, stream>>>(xlT, w1b, h1T, conv1_b, conv1_b, conv1_b,
                                                nullptr, 1L << 20, 0, 1L << 22, 0,
                                                1024, 4096, 1024, 1);
    // 10. conv2: out0[b] = conv2_w @ h1T[b]^T + b2 + x[b]  (M=1024,N=1024,K=4096)
    gemm_bt<<<dim3(8, 8, 4), 256, 0, stream>>>(w2b, h1T, out0, conv2_b, conv2_b, conv2_b,
                                               x, 0, 1L << 22, 1L << 20, 1L << 20,
                                               1024, 1024, 4096, 2);
}

// Round 3
// 677.235 us; speedup vs baseline: 1.1122x; 1.1122x over previous
//
#include <hip/hip_runtime.h>
#include <hip/hip_bf16.h>
#include <math.h>

// TransBlock on MI355X (gfx950). bf16 MFMA everywhere (threshold = 2% of absmax).
// R2: fix nontemporal-store type (ext_vector_type float4, not HIP float4 struct).
// R1 changes: conv2 split-K (2-way, 512 blocks) + add-reduce; two-phase LN stats;
// attn weights written via LDS as coalesced nontemporal float4 (bf16-rounded).

typedef __bf16 bf16;
typedef __bf16 bf16x4 __attribute__((ext_vector_type(4)));
typedef __bf16 bf16x8 __attribute__((ext_vector_type(8)));
typedef float floatx4 __attribute__((ext_vector_type(4)));

#define MFMA16(a, b, c) __builtin_amdgcn_mfma_f32_16x16x32_bf16(a, b, c, 0, 0, 0)

__device__ __forceinline__ void gload16(const void* g, void* l) {
    __builtin_amdgcn_global_load_lds((__attribute__((address_space(1))) void*)g,
                                     (__attribute__((address_space(3))) void*)l,
                                     16, 0, 0);
}

// ---------------- cast fp32 -> bf16 for the 5 weight matrices ----------------
__global__ __launch_bounds__(256)
void cast_all(const float* __restrict__ s0, bf16* __restrict__ d0_,
              const float* __restrict__ s1, bf16* __restrict__ d1_,
              const float* __restrict__ s2, bf16* __restrict__ d2_,
              const float* __restrict__ s3, bf16* __restrict__ d3_,
              const float* __restrict__ s4, bf16* __restrict__ d4_)
{
    int blk = blockIdx.x;
    const float* s; bf16* d; int base;
    if (blk < 1024)      { s = s0; d = d0_; base = blk; }
    else if (blk < 2048) { s = s1; d = d1_; base = blk - 1024; }
    else if (blk < 3072) { s = s2; d = d2_; base = blk - 2048; }
    else if (blk < 7168) { s = s3; d = d3_; base = blk - 3072; }
    else                 { s = s4; d = d4_; base = blk - 7168; }
    long i = ((long)base << 10) + (threadIdx.x << 2);
    float4 v = *(const float4*)(s + i);
    bf16x4 o;
    o[0] = (bf16)v.x; o[1] = (bf16)v.y; o[2] = (bf16)v.z; o[3] = (bf16)v.w;
    *(bf16x4*)(d + i) = o;
}

// ------------- LN stats phase 1: partial sum/sumsq over 256-c chunk ----------
// grid (16 d-tiles, 4 c-chunks, 4 b), block 256 (64 d-lanes x 4 c-groups)
__global__ __launch_bounds__(256)
void stats_part(const float* __restrict__ xin, float* __restrict__ ps,
                float* __restrict__ pq)
{
    __shared__ float S1[4][64];
    __shared__ float S2[4][64];
    const int b = blockIdx.z, chunk = blockIdx.y;
    const int d0 = blockIdx.x << 6;
    const int tid = threadIdx.x;
    const int dl = tid & 63, cg = tid >> 6;
    const float* xp = xin + ((long)b << 20) + d0 + dl;
    const int cbase = (chunk << 8) + (cg << 6);
    float s = 0.f, sq = 0.f;
    for (int c = 0; c < 64; ++c) {
        float v = xp[(long)(cbase + c) << 10];
        s += v; sq += v * v;
    }
    S1[cg][dl] = s; S2[cg][dl] = sq;
    __syncthreads();
    if (tid < 64) {
        float ts = S1[0][tid] + S1[1][tid] + S1[2][tid] + S1[3][tid];
        float tq = S2[0][tid] + S2[1][tid] + S2[2][tid] + S2[3][tid];
        int idx = ((b * 4 + chunk) << 10) + d0 + tid;
        ps[idx] = ts; pq[idx] = tq;
    }
}

// ------------- LN stats phase 2: combine 4 chunks -> mean/rstd ---------------
__global__ __launch_bounds__(256)
void stats_fin(const float* __restrict__ ps, const float* __restrict__ pq,
               float* __restrict__ u, float* __restrict__ rstd)
{
    int i = (blockIdx.x << 8) + threadIdx.x;     // [0,4096): b*1024+d
    int b = i >> 10, d = i & 1023;
    int base = (b << 12) + d;
    float s = ps[base] + ps[base + 1024] + ps[base + 2048] + ps[base + 3072];
    float q = pq[base] + pq[base + 1024] + pq[base + 2048] + pq[base + 3072];
    float mu = s * (1.f / 1024.f);
    float var = q * (1.f / 1024.f) - mu * mu;
    u[i] = mu;
    rstd[i] = rsqrtf(var + 1e-6f);
}

// ------------- normalize x1 three ways (q/k/v scale+shift), cast bf16 --------
__global__ __launch_bounds__(256)
void ln_qkv_kernel(const float* __restrict__ x1, const float* __restrict__ u,
                   const float* __restrict__ rs,
                   const float* __restrict__ wq, const float* __restrict__ bq,
                   const float* __restrict__ wk, const float* __restrict__ bk,
                   const float* __restrict__ wv, const float* __restrict__ bv,
                   bf16* __restrict__ lnq, bf16* __restrict__ lnk,
                   bf16* __restrict__ lnv)
{
    const int bc = blockIdx.x;             // b*1024 + c
    const int c = bc & 1023, b = bc >> 10;
    const int d = threadIdx.x << 2;
    const long i = ((long)bc << 10) + d;
    const float4 xv = *(const float4*)(x1 + i);
    const float4 uv = *(const float4*)(u + (b << 10) + d);
    const float4 rv = *(const float4*)(rs + (b << 10) + d);
    float xn0 = (xv.x - uv.x) * rv.x;
    float xn1 = (xv.y - uv.y) * rv.y;
    float xn2 = (xv.z - uv.z) * rv.z;
    float xn3 = (xv.w - uv.w) * rv.w;
    float sw, sb; bf16x4 o;
    sw = wq[c]; sb = bq[c];
    o[0]=(bf16)(sw*xn0+sb); o[1]=(bf16)(sw*xn1+sb); o[2]=(bf16)(sw*xn2+sb); o[3]=(bf16)(sw*xn3+sb);
    *(bf16x4*)(lnq + i) = o;
    sw = wk[c]; sb = bk[c];
    o[0]=(bf16)(sw*xn0+sb); o[1]=(bf16)(sw*xn1+sb); o[2]=(bf16)(sw*xn2+sb); o[3]=(bf16)(sw*xn3+sb);
    *(bf16x4*)(lnk + i) = o;
    sw = wv[c]; sb = bv[c];
    o[0]=(bf16)(sw*xn0+sb); o[1]=(bf16)(sw*xn1+sb); o[2]=(bf16)(sw*xn2+sb); o[3]=(bf16)(sw*xn3+sb);
    *(bf16x4*)(lnv + i) = o;
}

// --------- m97-style BT GEMM: out[m,n] = sum_k A[m,k]*B[n,k], 128x128 tile ----
// z -> (zb = z/zdiv, kz = z%zdiv); k range = [kz*Ksub, (kz+1)*Ksub)
// mode 0: out bf16 = acc + bias[n]              (QKV)
// mode 1: out bf16 = gelu(acc + bias[n])        (conv1 -> h1^T)
// mode 2: fp32: kz==0 -> Out = acc+bias[m]+R ;  kz>0 -> Part = acc (raw)
__global__ __launch_bounds__(256)
void gemm_bt(const bf16* __restrict__ Ab, const bf16* __restrict__ Bb,
             void* __restrict__ Outb, float* __restrict__ Part,
             const float* __restrict__ bias0, const float* __restrict__ bias1,
             const float* __restrict__ bias2, const float* __restrict__ residb,
             long sAz, long sBz, long sOz, long sRz, long sPz,
             int M, int N, int K, int Ksub, int zdiv, int mode)
{
    __shared__ __align__(16) bf16 As[128 * 32];
    __shared__ __align__(16) bf16 Bs[128 * 32];
    const int z = blockIdx.z;
    const int zb = z / zdiv, kz = z % zdiv;
    const bf16* A = Ab + (long)zb * sAz + (long)kz * Ksub;
    const bf16* B = Bb + (long)zb * sBz + (long)kz * Ksub;
    const float* bias = (zb == 0) ? bias0 : (zb == 1 ? bias1 : bias2);
    const int m0 = blockIdx.y << 7, n0 = blockIdx.x << 7;
    const int tid = threadIdx.x;
    const int wave = tid >> 6, lane = tid & 63;
    const int wm = (wave & 1) << 6, wn = (wave >> 1) << 6;
    const int lm = lane & 15, lk = (lane >> 4) << 3;
    floatx4 acc[4][4] = {};
    for (int kt = 0; kt < Ksub; kt += 32) {
        const bf16* Ag = A + (long)m0 * K + kt;
        const bf16* Bg = B + (long)n0 * K + kt;
#pragma unroll
        for (int i = 0; i < 2; ++i) {
            int c = tid + (i << 8);
            int row = c >> 2, kc = (c & 3) << 3;
            gload16(Ag + (long)row * K + kc, As + c * 8);
            gload16(Bg + (long)row * K + kc, Bs + c * 8);
        }
        __syncthreads();
        bf16x8 af[4], bfv[4];
#pragma unroll
        for (int mi = 0; mi < 4; ++mi)
            af[mi] = *(const bf16x8*)(As + (wm + mi * 16 + lm) * 32 + lk);
#pragma unroll
        for (int ni = 0; ni < 4; ++ni)
            bfv[ni] = *(const bf16x8*)(Bs + (wn + ni * 16 + lm) * 32 + lk);
#pragma unroll
        for (int mi = 0; mi < 4; ++mi)
#pragma unroll
            for (int ni = 0; ni < 4; ++ni)
                acc[mi][ni] = MFMA16(af[mi], bfv[ni], acc[mi][ni]);
        __syncthreads();
    }
    const int quad = lane >> 4;
    if (mode == 2) {
        if (kz == 0) {
            float* Out = (float*)Outb + (long)zb * sOz;
            const float* R = residb + (long)zb * sRz;
#pragma unroll
            for (int mi = 0; mi < 4; ++mi)
#pragma unroll
                for (int ni = 0; ni < 4; ++ni)
#pragma unroll
                    for (int r = 0; r < 4; ++r) {
                        int row = m0 + wm + mi * 16 + quad * 4 + r;
                        int col = n0 + wn + ni * 16 + lm;
                        long idx = (long)row * N + col;
                        Out[idx] = acc[mi][ni][r] + bias[row] + R[idx];
                    }
        } else {
            float* Out = Part + (long)zb * sPz;
#pragma unroll
            for (int mi = 0; mi < 4; ++mi)
#pragma unroll
                for (int ni = 0; ni < 4; ++ni)
#pragma unroll
                    for (int r = 0; r < 4; ++r) {
                        int row = m0 + wm + mi * 16 + quad * 4 + r;
                        int col = n0 + wn + ni * 16 + lm;
                        Out[(long)row * N + col] = acc[mi][ni][r];
                    }
        }
    } else {
        bf16* Out = (bf16*)Outb + (long)zb * sOz;
#pragma unroll
        for (int mi = 0; mi < 4; ++mi)
#pragma unroll
            for (int ni = 0; ni < 4; ++ni)
#pragma unroll
                for (int r = 0; r < 4; ++r) {
                    int row = m0 + wm + mi * 16 + quad * 4 + r;
                    int col = n0 + wn + ni * 16 + lm;
                    float v = acc[mi][ni][r] + bias[col];
                    if (mode == 1)
                        v = 0.5f * v * (1.0f + erff(v * 0.70710678118654752f));
                    Out[(long)row * N + col] = (bf16)v;
                }
    }
}

// ------------------ out0 += part (split-K reduce), float4 --------------------
__global__ __launch_bounds__(256)
void addpart(float* __restrict__ out, const float* __restrict__ part)
{
    long i = (((long)blockIdx.x << 8) + threadIdx.x) << 2;
    float4 o = *(const float4*)(out + i);
    float4 p = *(const float4*)(part + i);
    o.x += p.x; o.y += p.y; o.z += p.z; o.w += p.w;
    *(float4*)(out + i) = o;
}

// ---------------- V slab transpose: VT[p][e][k] = V[p][k][e] ------------------
__global__ __launch_bounds__(256)
void vtrans_kernel(const bf16* __restrict__ v, bf16* __restrict__ vt)
{
    __shared__ bf16 T[64][66];
    const int p = blockIdx.y;
    const int k0 = blockIdx.x << 6;
    const bf16* V = v + ((long)p << 16);
    bf16* Vt = vt + ((long)p << 16);
    const int tid = threadIdx.x;
    const int e = tid & 63, g = tid >> 6;
#pragma unroll
    for (int j = 0; j < 16; ++j) {
        int kk = (g << 4) + j;
        T[e][kk] = V[((long)(k0 + kk) << 6) + e];
    }
    __syncthreads();
#pragma unroll
    for (int j = 0; j < 16; ++j) {
        int er = (g << 4) + j;
        Vt[((long)er << 10) + k0 + e] = T[er][e];
    }
}

// ------- fused attention: S=QK^T/8, softmax-one, write weights, PV, +x1 -------
__global__ __launch_bounds__(256)
void attn_kernel(const bf16* __restrict__ q, const bf16* __restrict__ k,
                 const bf16* __restrict__ vt, const float* __restrict__ x1,
                 float* __restrict__ attw, float* __restrict__ x)
{
    __shared__ __align__(16) bf16 Wl[16][1032];   // weights (bf16): PV A-op + attw source
    __shared__ float red[16][4];
    const int s = blockIdx.x;            // q-stripe 0..63
    const int p = blockIdx.y;            // (b,h) 0..63
    const int b = p >> 4, h = p & 15;
    const bf16* Qp = q + ((long)b << 20) + ((long)h << 16);
    const bf16* Kp = k + ((long)b << 20) + ((long)h << 16);
    const bf16* Vt = vt + ((long)p << 16);
    const int tid = threadIdx.x, w = tid >> 6, lane = tid & 63;
    const int lm = lane & 15, quad = lane >> 4;
    const int r0 = s << 4, kc0 = w << 8;

    floatx4 acc[16];
#pragma unroll
    for (int t = 0; t < 16; ++t) acc[t] = (floatx4){0.f, 0.f, 0.f, 0.f};

#pragma unroll
    for (int e0 = 0; e0 < 64; e0 += 32) {
        bf16x8 aq = *(const bf16x8*)(Qp + ((long)(r0 + lm) << 6) + e0 + quad * 8);
#pragma unroll
        for (int t = 0; t < 16; ++t) {
            bf16x8 bk = *(const bf16x8*)(Kp + ((long)(kc0 + t * 16 + lm) << 6) + e0 + quad * 8);
            acc[t] = MFMA16(aq, bk, acc[t]);
        }
    }
#pragma unroll
    for (int t = 0; t < 16; ++t)
#pragma unroll
        for (int r = 0; r < 4; ++r) acc[t][r] *= 0.125f;   // 1/sqrt(64)

    float mloc[4];
#pragma unroll
    for (int r = 0; r < 4; ++r) {
        float mm = acc[0][r];
#pragma unroll
        for (int t = 1; t < 16; ++t) mm = fmaxf(mm, acc[t][r]);
        mloc[r] = mm;
    }
#pragma unroll
    for (int off = 1; off < 16; off <<= 1)
#pragma unroll
        for (int r = 0; r < 4; ++r) mloc[r] = fmaxf(mloc[r], __shfl_xor(mloc[r], off, 64));
    if (lm == 0)
#pragma unroll
        for (int r = 0; r < 4; ++r) red[quad * 4 + r][w] = mloc[r];
    __syncthreads();
    float mfin[4];
#pragma unroll
    for (int r = 0; r < 4; ++r) {
        int row = quad * 4 + r;
        mfin[r] = fmaxf(fmaxf(red[row][0], red[row][1]), fmaxf(red[row][2], red[row][3]));
    }
    float sloc[4] = {0.f, 0.f, 0.f, 0.f};
#pragma unroll
    for (int t = 0; t < 16; ++t)
#pragma unroll
        for (int r = 0; r < 4; ++r) {
            float e = __expf(acc[t][r] - mfin[r]);
            acc[t][r] = e;
            sloc[r] += e;
        }
#pragma unroll
    for (int off = 1; off < 16; off <<= 1)
#pragma unroll
        for (int r = 0; r < 4; ++r) sloc[r] += __shfl_xor(sloc[r], off, 64);
    __syncthreads();
    if (lm == 0)
#pragma unroll
        for (int r = 0; r < 4; ++r) red[quad * 4 + r][w] = sloc[r];
    __syncthreads();
    float inv[4];
#pragma unroll
    for (int r = 0; r < 4; ++r) {
        int row = quad * 4 + r;
        inv[r] = 1.f / (1.f + red[row][0] + red[row][1] + red[row][2] + red[row][3]);
    }
    // normalized weights -> LDS (bf16) only; global write comes later, coalesced
#pragma unroll
    for (int r = 0; r < 4; ++r) {
        int row = quad * 4 + r;
        float iv = inv[r];
#pragma unroll
        for (int t = 0; t < 16; ++t)
            Wl[row][kc0 + t * 16 + lm] = (bf16)(acc[t][r] * iv);
    }
    __syncthreads();

    // PV: O(16x64) = W(16x1024) @ V(1024x64), wave w covers k in [kc0,kc0+256)
    floatx4 opv[4];
#pragma unroll
    for (int ni = 0; ni < 4; ++ni) opv[ni] = (floatx4){0.f, 0.f, 0.f, 0.f};
#pragma unroll
    for (int i = 0; i < 8; ++i) {
        const int kk = kc0 + i * 32;
        bf16x8 a0 = *(const bf16x8*)&Wl[lm][kk + quad * 8];
#pragma unroll
        for (int ni = 0; ni < 4; ++ni) {
            bf16x8 bv = *(const bf16x8*)(Vt + ((long)(ni * 16 + lm) << 10) + kk + quad * 8);
            opv[ni] = MFMA16(a0, bv, opv[ni]);
        }
    }
    // coalesced attw write from Wl: 16 rows x 1024 cols fp32, float4/lane/iter
    {
        float* attp = attw + ((long)p << 20) + ((long)r0 << 10);
#pragma unroll
        for (int i = 0; i < 16; ++i) {
            int v4 = (i << 8) + tid;
            int row = v4 >> 8, col = (v4 & 255) << 2;
            bf16x4 wv = *(const bf16x4*)&Wl[row][col];
            floatx4 o = {(float)wv[0], (float)wv[1], (float)wv[2], (float)wv[3]};
            __builtin_nontemporal_store(o, (floatx4*)(attp + ((long)row << 10) + col));
        }
    }
    __syncthreads();
    float* Ored = (float*)&Wl[0][0];   // [4][16][64], aliases Wl (dead now)
#pragma unroll
    for (int ni = 0; ni < 4; ++ni)
#pragma unroll
        for (int r = 0; r < 4; ++r)
            Ored[(w * 16 + quad * 4 + r) * 64 + ni * 16 + lm] = opv[ni][r];
    __syncthreads();
    const float* x1p = x1 + ((long)b << 20) + ((long)r0 << 10) + (h << 6);
    float* xp = x + ((long)b << 20) + ((long)r0 << 10) + (h << 6);
#pragma unroll
    for (int j = 0; j < 4; ++j) {
        int el = tid + (j << 8);
        int row = el >> 6, cc = el & 63;
        float o = Ored[row * 64 + cc] + Ored[(16 + row) * 64 + cc]
                + Ored[(32 + row) * 64 + cc] + Ored[(48 + row) * 64 + cc];
        xp[((long)row << 10) + cc] = x1p[((long)row << 10) + cc] + o;
    }
}

// --------- FFN LN + transpose: xlT[b][l][c] = ffw[c]*(x-u)*rstd + ffb[c] ------
__global__ __launch_bounds__(256)
void ln_ffn_t_kernel(const float* __restrict__ x, const float* __restrict__ u2,
                     const float* __restrict__ r2, const float* __restrict__ fw,
                     const float* __restrict__ fb, bf16* __restrict__ xlT)
{
    __shared__ bf16 T[64][66];
    const int b = blockIdx.z;
    const int l0 = blockIdx.x << 6, c0 = blockIdx.y << 6;
    const int tid = threadIdx.x;
    const int ll = tid & 63, g = tid >> 6;
    const float uu = u2[(b << 10) + l0 + ll];
    const float rr = r2[(b << 10) + l0 + ll];
#pragma unroll
    for (int j = 0; j < 16; ++j) {
        int cc = (g << 4) + j;
        float v = x[((long)b << 20) + ((long)(c0 + cc) << 10) + l0 + ll];
        T[ll][cc] = (bf16)(fw[c0 + cc] * (v - uu) * rr + fb[c0 + cc]);
    }
    __syncthreads();
#pragma unroll
    for (int j = 0; j < 16; ++j) {
        int lr = (g << 4) + j;
        xlT[((long)b << 20) + ((long)(l0 + lr) << 10) + c0 + ll] = T[lr][ll];
    }
}

extern "C" void kernel_launch(void* const* d_in, const int* in_sizes, int n_in,
                              void* d_out, int out_size, void* d_ws, size_t ws_size,
                              hipStream_t stream)
{
    const float* x1      = (const float*)d_in[0];
    const float* lnq_w   = (const float*)d_in[1];
    const float* lnq_b   = (const float*)d_in[2];
    const float* lnk_w   = (const float*)d_in[3];
    const float* lnk_b   = (const float*)d_in[4];
    const float* lnv_w   = (const float*)d_in[5];
    const float* lnv_b   = (const float*)d_in[6];
    const float* wq      = (const float*)d_in[7];
    const float* bq      = (const float*)d_in[8];
    const float* wk      = (const float*)d_in[9];
    const float* bk      = (const float*)d_in[10];
    const float* wv      = (const float*)d_in[11];
    const float* bv      = (const float*)d_in[12];
    const float* ffnln_w = (const float*)d_in[13];
    const float* ffnln_b = (const float*)d_in[14];
    const float* conv1_w = (const float*)d_in[15];
    const float* conv1_b = (const float*)d_in[16];
    const float* conv2_w = (const float*)d_in[17];
    const float* conv2_b = (const float*)d_in[18];
    (void)in_sizes; (void)n_in; (void)out_size; (void)ws_size;

    char* ws = (char*)d_ws;
    // header: u1 r1 u2 r2 (16KB each) + ps/pq partials (64KB each) -> 256KB
    const size_t OFF_VT   = 262144;                   //  8 MB VT        [h1T overlay]
    const size_t OFF_QKV  = OFF_VT   + 8388608;       // 24 MB q,k,v bf16 [h1T overlay]
    const size_t OFF_WQKV = OFF_QKV  + 25165824;      //  8 MB wq/wk/wv bf16 [xlT / part overlay]
    const size_t OFF_W1   = OFF_WQKV + 8388608;       //  8 MB conv1_w bf16  [part overlay]
    const size_t OFF_X    = OFF_W1   + 8388608;       // 16 MB x = x1 + attn_out (fp32)
    const size_t OFF_W2   = OFF_X    + 16777216;      //  8 MB conv2_w bf16
    float* u1    = (float*)(ws + 0);
    float* r1    = (float*)(ws + 16384);
    float* u2    = (float*)(ws + 32768);
    float* r2    = (float*)(ws + 49152);
    float* ps    = (float*)(ws + 65536);
    float* pq    = (float*)(ws + 131072);
    bf16*  vt    = (bf16*)(ws + OFF_VT);
    bf16*  qkv   = (bf16*)(ws + OFF_QKV);
    bf16*  wqkvb = (bf16*)(ws + OFF_WQKV);
    bf16*  w1b   = (bf16*)(ws + OFF_W1);
    float* x     = (float*)(ws + OFF_X);
    bf16*  w2b   = (bf16*)(ws + OFF_W2);
    bf16*  h1T   = (bf16*)(ws + OFF_VT);              // 32 MB, overlays vt+qkv (dead post-attn)
    bf16*  xlT   = (bf16*)(ws + OFF_WQKV);            //  8 MB, overlays wqkvb (dead post-QKV)
    float* part  = (float*)(ws + OFF_WQKV);           // 16 MB, overlays wqkvb+w1b (dead at conv2)

    float* out0 = (float*)d_out;
    float* attw = (float*)((char*)d_out + 16777216);  // 4*16*1024*1024 fp32
    bf16*  lnqkv = (bf16*)attw;                       // 24 MB scratch, dead before attn writes

    // 1. weight casts
    cast_all<<<11264, 256, 0, stream>>>(wq, wqkvb, wk, wqkvb + (1 << 20),
                                        wv, wqkvb + (2 << 20), conv1_w, w1b, conv2_w, w2b);
    // 2. LN stats of x1 (two-phase)
    stats_part<<<dim3(16, 4, 4), 256, 0, stream>>>(x1, ps, pq);
    stats_fin<<<16, 256, 0, stream>>>(ps, pq, u1, r1);
    // 3. normalized q/k/v inputs (bf16)
    ln_qkv_kernel<<<4096, 256, 0, stream>>>(x1, u1, r1, lnq_w, lnq_b, lnk_w, lnk_b,
                                            lnv_w, lnv_b, lnqkv, lnqkv + (1L << 22),
                                            lnqkv + (2L << 22));
    // 4. QKV projections (z=0/1/2), bf16 out + bias
    gemm_bt<<<dim3(8, 32, 3), 256, 0, stream>>>(lnqkv, wqkvb, qkv, nullptr, bq, bk, bv,
                                                nullptr, 1L << 22, 1L << 20, 1L << 22, 0, 0,
                                                4096, 1024, 1024, 1024, 1, 0);
    // 5. V^T slabs for PV B-operand
    vtrans_kernel<<<dim3(16, 64), 256, 0, stream>>>(qkv + (2L << 22), vt);
    // 6. fused attention (attn weights fp32 + x = x1 + o)
    attn_kernel<<<dim3(64, 64), 256, 0, stream>>>(qkv, qkv + (1L << 22), vt, x1, attw, x);
    // 7. FFN LN stats of x (two-phase)
    stats_part<<<dim3(16, 4, 4), 256, 0, stream>>>(x, ps, pq);
    stats_fin<<<16, 256, 0, stream>>>(ps, pq, u2, r2);
    // 8. FFN LN + transpose -> xlT (bf16)
    ln_ffn_t_kernel<<<dim3(16, 16, 4), 256, 0, stream>>>(x, u2, r2, ffnln_w, ffnln_b, xlT);
    // 9. conv1: h1T[b] = gelu(xlT[b] @ conv1_w^T + b1)   (M=1024,N=4096,K=1024)
    gemm_bt<<<dim3(32, 8, 4), 256, 0, stream>>>(xlT, w1b, h1T, nullptr, conv1_b, conv1_b,
                                                conv1_b, nullptr, 1L << 20, 0, 1L << 22, 0, 0,
                                                1024, 4096, 1024, 1024, 1, 1);
    // 10. conv2 split-K: out0[b] = conv2_w @ h1T[b]^T + b2 + x[b]  (K=4096 -> 2x2048)
    gemm_bt<<<dim3(8, 8, 8), 256, 0, stream>>>(w2b, h1T, out0, part, conv2_b, conv2_b,
                                               conv2_b, x, 0, 1L << 22, 1L << 20, 1L << 20,
                                               1L << 20, 1024, 1024, 4096, 2048, 2, 2);
    // 11. out0 += part
    addpart<<<4096, 256, 0, stream>>>(out0, part);
}